// Round 14
// baseline (299.083 us; speedup 1.0000x reference)
//
#include <hip/hip_runtime.h>
#include <hip/hip_bf16.h>

#define ENC_DIM 2048
#define DEC_DIM 512
#define ATT_DIM 512
#define NB 256
#define NP 196
#define M_TOT (NB * NP)   // 50176 = 784 * 64
#define BM 64
#define BK 32
#define NSTEP (ENC_DIM / BK)  // 64

typedef __attribute__((ext_vector_type(8))) short short8;
typedef __attribute__((ext_vector_type(4))) float f32x4;

__device__ __forceinline__ short8 cvt8v(f32x4 x, f32x4 y) {
    union { short8 v; __hip_bfloat16 h[8]; } u;
    u.h[0] = __float2bfloat16(x[0]);
    u.h[1] = __float2bfloat16(x[1]);
    u.h[2] = __float2bfloat16(x[2]);
    u.h[3] = __float2bfloat16(x[3]);
    u.h[4] = __float2bfloat16(y[0]);
    u.h[5] = __float2bfloat16(y[1]);
    u.h[6] = __float2bfloat16(y[2]);
    u.h[7] = __float2bfloat16(y[3]);
    return u.v;
}

// ---------------------------------------------------------------------------
// Kernel 1 (fused): blocks [0,512): pack W_enc into Btt tiled:
//   short-offset = S*16384 + fr*512 + kg*128 + l15*8 holds
//   bf16 W[k = S*32+kg*8 .. +8][col = fr*16+l15]
// => B fragment fr of K-step S is one contiguous 1KB wave load from L2.
// blocks [512,768): att2f = dec@W_dec + b_dec + b_enc.
// ---------------------------------------------------------------------------
__global__ __launch_bounds__(256) void prep_kernel(const float* __restrict__ W,
                                                   __hip_bfloat16* __restrict__ Btt,
                                                   const float* __restrict__ dec,
                                                   const float* __restrict__ W_dec,
                                                   const float* __restrict__ b_dec,
                                                   const float* __restrict__ b_enc,
                                                   float* __restrict__ att2f) {
    __shared__ float ds[DEC_DIM];
    if (blockIdx.x < 512) {
        const int gid = blockIdx.x * 256 + threadIdx.x;  // 0..131071
        const int s   = gid >> 11;        // K-step 0..63
        const int u   = gid & 2047;       // unit within step
        const int fr  = u >> 6;           // col block 0..31
        const int kg  = (u >> 4) & 3;
        const int l15 = u & 15;
        const int col = fr * 16 + l15;
        const int k0  = s * 32 + kg * 8;
        union { short8 v; __hip_bfloat16 h[8]; } x;
        #pragma unroll
        for (int i = 0; i < 8; ++i)
            x.h[i] = __float2bfloat16(W[(size_t)(k0 + i) * ATT_DIM + col]);
        *(short8*)((short*)Btt + (size_t)gid * 8) = x.v;
    } else {
        const int b = blockIdx.x - 512;
        const int t = threadIdx.x;
        ds[t]       = dec[(size_t)b * DEC_DIM + t];
        ds[t + 256] = dec[(size_t)b * DEC_DIM + t + 256];
        __syncthreads();
        #pragma unroll
        for (int j = 0; j < 2; ++j) {
            const int n = t + j * 256;
            float s = 0.f;
            #pragma unroll 8
            for (int k = 0; k < DEC_DIM; ++k)
                s += ds[k] * W_dec[(size_t)k * ATT_DIM + n];
            att2f[(size_t)b * ATT_DIM + n] = s + b_dec[n] + b_enc[n];
        }
    }
}

// ---------------------------------------------------------------------------
// Kernel 2: e[m] = sum_n relu(enc[m,:]@W_enc[:,n] + att2f[b,n]) * W_att[n]
// RESIDENT-A, BARRIER-FREE K-LOOP. BM=64 x BN=512; 8 waves, wave tile 64x64.
// Two K-phases of 1024: per phase, stage A(64x1024 bf16 = 128 KB) into LDS
// (one __syncthreads pair), then a 32-step loop with ZERO barriers:
//   A-frags: read-only LDS (contiguous 1KB wave reads, conflict-free).
//   B: L2 -> registers from pre-tiled Btt, named double-buffer (r9-proven).
// acc persists across phases. Waves drift freely: no straggler coupling.
// ---------------------------------------------------------------------------
__global__ __launch_bounds__(512, 2) void e_kernel(const float* __restrict__ enc,
                                                   const short* __restrict__ Btt,
                                                   const float* __restrict__ att2f,
                                                   const float* __restrict__ W_att,
                                                   float* __restrict__ e_out) {
    // A LDS: 32 steps x 256 units x 16B = 128 KB. unit = s*256 + mf*64 + kg*16 + l15
    __shared__ __attribute__((aligned(16))) short As[32 * 256 * 8];
    __shared__ float ebuf[8][64];

    const int tid  = threadIdx.x;
    const int lane = tid & 63;
    const int wv   = tid >> 6;   // 0..7 : 64-col slice
    const int l15  = lane & 15;
    const int kg   = lane >> 4;  // 0..3
    const int M0   = blockIdx.x * BM;

    // staging: thread -> (row = tid>>3, base k-chunk sc = tid&7); 16 iters
    const int srow = tid >> 3;
    const int sc   = tid & 7;
    const float* sbase = enc + (size_t)(M0 + srow) * ENC_DIM + sc * 8;
    // LDS short index for iter i: unit = ((sc>>2)+2i)*256 + (srow>>4)*64 + (sc&3)*16 + (srow&15)
    const int wbase = (((sc >> 2) * 256) + ((srow >> 4) * 64) + ((sc & 3) * 16) + (srow & 15)) * 8;

    // B fragment base: frag nf of step S at short-offset S*16384 + (wv*4+nf)*512 + kg*128 + l15*8
    const short* pBb = Btt + wv * 2048 + kg * 128 + l15 * 8;

    f32x4 acc[4][4];
    #pragma unroll
    for (int i = 0; i < 4; ++i)
        #pragma unroll
        for (int j = 0; j < 4; ++j)
            acc[i][j] = (f32x4){0.f, 0.f, 0.f, 0.f};

#define MFMA16(A0, A1, A2, A3, B0, B1, B2, B3)                                       \
    acc[0][0] = __builtin_amdgcn_mfma_f32_16x16x32_bf16(A0, B0, acc[0][0], 0, 0, 0); \
    acc[0][1] = __builtin_amdgcn_mfma_f32_16x16x32_bf16(A0, B1, acc[0][1], 0, 0, 0); \
    acc[0][2] = __builtin_amdgcn_mfma_f32_16x16x32_bf16(A0, B2, acc[0][2], 0, 0, 0); \
    acc[0][3] = __builtin_amdgcn_mfma_f32_16x16x32_bf16(A0, B3, acc[0][3], 0, 0, 0); \
    acc[1][0] = __builtin_amdgcn_mfma_f32_16x16x32_bf16(A1, B0, acc[1][0], 0, 0, 0); \
    acc[1][1] = __builtin_amdgcn_mfma_f32_16x16x32_bf16(A1, B1, acc[1][1], 0, 0, 0); \
    acc[1][2] = __builtin_amdgcn_mfma_f32_16x16x32_bf16(A1, B2, acc[1][2], 0, 0, 0); \
    acc[1][3] = __builtin_amdgcn_mfma_f32_16x16x32_bf16(A1, B3, acc[1][3], 0, 0, 0); \
    acc[2][0] = __builtin_amdgcn_mfma_f32_16x16x32_bf16(A2, B0, acc[2][0], 0, 0, 0); \
    acc[2][1] = __builtin_amdgcn_mfma_f32_16x16x32_bf16(A2, B1, acc[2][1], 0, 0, 0); \
    acc[2][2] = __builtin_amdgcn_mfma_f32_16x16x32_bf16(A2, B2, acc[2][2], 0, 0, 0); \
    acc[2][3] = __builtin_amdgcn_mfma_f32_16x16x32_bf16(A2, B3, acc[2][3], 0, 0, 0); \
    acc[3][0] = __builtin_amdgcn_mfma_f32_16x16x32_bf16(A3, B0, acc[3][0], 0, 0, 0); \
    acc[3][1] = __builtin_amdgcn_mfma_f32_16x16x32_bf16(A3, B1, acc[3][1], 0, 0, 0); \
    acc[3][2] = __builtin_amdgcn_mfma_f32_16x16x32_bf16(A3, B2, acc[3][2], 0, 0, 0); \
    acc[3][3] = __builtin_amdgcn_mfma_f32_16x16x32_bf16(A3, B3, acc[3][3], 0, 0, 0);

    for (int p = 0; p < 2; ++p) {
        // ---- stage A for this phase (only barriers in the kernel) ----
        __syncthreads();   // phase-0 trivial; phase-1: all reads of As done
        {
            const float* sp = sbase + (size_t)p * 1024;
            #pragma unroll
            for (int i = 0; i < 16; ++i) {
                f32x4 lo = *(const f32x4*)(sp + i * 64);
                f32x4 hi = *(const f32x4*)(sp + i * 64 + 4);
                *(short8*)&As[wbase + i * 4096] = cvt8v(lo, hi);
            }
        }
        __syncthreads();

        // ---- barrier-free 32-step loop ----
        const int S0 = p * 32;
        const short* pb0 = pBb + (size_t)S0 * 16384;
        short8 c0 = *(const short8*)(pb0);
        short8 c1 = *(const short8*)(pb0 + 512);
        short8 c2 = *(const short8*)(pb0 + 1024);
        short8 c3 = *(const short8*)(pb0 + 1536);
        short8 n0, n1, n2, n3;

        for (int s = 0; s < 32; s += 2) {
            // even: consume (c*, A[s]); prefetch n* = B(S0+s+1)
            {
                const short* p1 = pBb + (size_t)(S0 + s + 1) * 16384;
                n0 = *(const short8*)(p1);
                n1 = *(const short8*)(p1 + 512);
                n2 = *(const short8*)(p1 + 1024);
                n3 = *(const short8*)(p1 + 1536);
                __builtin_amdgcn_sched_barrier(0);
                const short* Ab = &As[s * 2048];
                const short8 a0 = *(const short8*)&Ab[0 * 512 + lane * 8];
                const short8 a1 = *(const short8*)&Ab[1 * 512 + lane * 8];
                const short8 a2 = *(const short8*)&Ab[2 * 512 + lane * 8];
                const short8 a3 = *(const short8*)&Ab[3 * 512 + lane * 8];
                __builtin_amdgcn_s_setprio(1);
                MFMA16(a0, a1, a2, a3, c0, c1, c2, c3)
                __builtin_amdgcn_s_setprio(0);
            }
            // odd: consume (n*, A[s+1]); prefetch c* = B((S0+s+2) & 63)
            {
                const short* p2 = pBb + (size_t)((S0 + s + 2) & 63) * 16384;
                c0 = *(const short8*)(p2);
                c1 = *(const short8*)(p2 + 512);
                c2 = *(const short8*)(p2 + 1024);
                c3 = *(const short8*)(p2 + 1536);
                __builtin_amdgcn_sched_barrier(0);
                const short* Ab = &As[(s + 1) * 2048];
                const short8 a0 = *(const short8*)&Ab[0 * 512 + lane * 8];
                const short8 a1 = *(const short8*)&Ab[1 * 512 + lane * 8];
                const short8 a2 = *(const short8*)&Ab[2 * 512 + lane * 8];
                const short8 a3 = *(const short8*)&Ab[3 * 512 + lane * 8];
                __builtin_amdgcn_s_setprio(1);
                MFMA16(a0, a1, a2, a3, n0, n1, n2, n3)
                __builtin_amdgcn_s_setprio(0);
            }
        }
    }
#undef MFMA16

    // epilogue: + att2, relu, * W_att, reduce over n
    float wat[4];
    #pragma unroll
    for (int nf = 0; nf < 4; ++nf) wat[nf] = W_att[wv * 64 + nf * 16 + l15];

    #pragma unroll
    for (int mf = 0; mf < 4; ++mf) {
        #pragma unroll
        for (int rr = 0; rr < 4; ++rr) {
            const int ml = mf * 16 + kg * 4 + rr;   // local row 0..63
            const int bb = (M0 + ml) / NP;
            const float* arow2 = att2f + (size_t)bb * ATT_DIM + wv * 64 + l15;
            float sv = 0.f;
            #pragma unroll
            for (int nf = 0; nf < 4; ++nf) {
                float v = acc[mf][nf][rr] + arow2[nf * 16];
                sv += fmaxf(v, 0.f) * wat[nf];
            }
            sv += __shfl_xor(sv, 1);
            sv += __shfl_xor(sv, 2);
            sv += __shfl_xor(sv, 4);
            sv += __shfl_xor(sv, 8);
            if (l15 == 0) ebuf[wv][ml] = sv;
        }
    }
    __syncthreads();
    if (tid < 64) {
        float sv = 0.f;
        #pragma unroll
        for (int w = 0; w < 8; ++w) sv += ebuf[w][tid];
        e_out[M0 + tid] = sv;
    }
}

// ---------------------------------------------------------------------------
// Kernel 3: per-batch softmax over 196 pixels + z[b,:] = sum_p alpha[b,p]*enc[b,p,:]
// grid (256, 2): 1024-col chunks, float4/thread, dual accumulators.
// ---------------------------------------------------------------------------
__global__ __launch_bounds__(256) void z_kernel(const float* __restrict__ enc,
                                                const float* __restrict__ e,
                                                float* __restrict__ z,
                                                float* __restrict__ alpha) {
    const int b  = blockIdx.x;
    const int cb = blockIdx.y;
    const int t  = threadIdx.x;
    __shared__ float al[NP];
    __shared__ float red[4];

    float ev = (t < NP) ? e[(size_t)b * NP + t] : -1e30f;
    float m = ev;
    #pragma unroll
    for (int o = 32; o > 0; o >>= 1) m = fmaxf(m, __shfl_xor(m, o));
    if ((t & 63) == 0) red[t >> 6] = m;
    __syncthreads();
    m = fmaxf(fmaxf(red[0], red[1]), fmaxf(red[2], red[3]));
    __syncthreads();
    float ex = (t < NP) ? __expf(ev - m) : 0.f;
    float s = ex;
    #pragma unroll
    for (int o = 32; o > 0; o >>= 1) s += __shfl_xor(s, o);
    if ((t & 63) == 0) red[t >> 6] = s;
    __syncthreads();
    s = red[0] + red[1] + red[2] + red[3];
    const float a = ex * (1.0f / s);
    if (t < NP) {
        al[t] = a;
        if (cb == 0) alpha[(size_t)b * NP + t] = a;
    }
    __syncthreads();

    const int c0 = cb * 1024 + t * 4;
    const float4* ep = (const float4*)(enc + (size_t)b * NP * ENC_DIM + c0);
    float4 z0 = make_float4(0.f, 0.f, 0.f, 0.f);
    float4 z1 = make_float4(0.f, 0.f, 0.f, 0.f);
    #pragma unroll 4
    for (int p = 0; p < NP; p += 2) {
        const float a0 = al[p];
        const float a1 = al[p + 1];
        const float4 v0 = ep[(size_t)p * (ENC_DIM / 4)];
        const float4 v1 = ep[(size_t)(p + 1) * (ENC_DIM / 4)];
        z0.x += a0 * v0.x; z0.y += a0 * v0.y; z0.z += a0 * v0.z; z0.w += a0 * v0.w;
        z1.x += a1 * v1.x; z1.y += a1 * v1.y; z1.z += a1 * v1.z; z1.w += a1 * v1.w;
    }
    z0.x += z1.x; z0.y += z1.y; z0.z += z1.z; z0.w += z1.w;
    *(float4*)(z + (size_t)b * ENC_DIM + c0) = z0;
}

// ---------------------------------------------------------------------------
extern "C" void kernel_launch(void* const* d_in, const int* in_sizes, int n_in,
                              void* d_out, int out_size, void* d_ws, size_t ws_size,
                              hipStream_t stream) {
    const float* enc   = (const float*)d_in[0];  // (256,196,2048)
    const float* dec   = (const float*)d_in[1];  // (256,512)
    const float* W_enc = (const float*)d_in[2];  // (2048,512)
    const float* b_enc = (const float*)d_in[3];  // (512)
    const float* W_dec = (const float*)d_in[4];  // (512,512)
    const float* b_dec = (const float*)d_in[5];  // (512)
    const float* W_att = (const float*)d_in[6];  // (512,1)
    // d_in[7] = b_att: softmax-invariant, unused.

    float* z     = (float*)d_out;                 // 256*2048
    float* alpha = z + (size_t)NB * ENC_DIM;      // 256*196

    char* ws = (char*)d_ws;
    __hip_bfloat16* Btt = (__hip_bfloat16*)ws;                        // 2 MB
    float* att2f        = (float*)(ws + 2 * 1024 * 1024);             // 512 KB
    float* e            = (float*)(ws + 2 * 1024 * 1024 + 512 * 1024);// 200 KB

    prep_kernel<<<768, 256, 0, stream>>>(W_enc, Btt, dec, W_dec, b_dec, b_enc, att2f);
    e_kernel<<<M_TOT / BM, 512, 0, stream>>>(enc, (const short*)Btt, att2f, W_att, e);
    z_kernel<<<dim3(NB, 2), 256, 0, stream>>>(enc, e, z, alpha);
}

// Round 15
// 293.241 us; speedup vs baseline: 1.0199x; 1.0199x over previous
//
#include <hip/hip_runtime.h>
#include <hip/hip_bf16.h>

#define ENC_DIM 2048
#define DEC_DIM 512
#define ATT_DIM 512
#define NB 256
#define NP 196
#define M_TOT (NB * NP)   // 50176 = 392 * 128
#define BM 128
#define BK 32
#define NSTEP (ENC_DIM / BK)  // 64

typedef __attribute__((ext_vector_type(8))) short short8;
typedef __attribute__((ext_vector_type(4))) float f32x4;

__device__ __forceinline__ short8 cvt8v(f32x4 x, f32x4 y) {
    union { short8 v; __hip_bfloat16 h[8]; } u;
    u.h[0] = __float2bfloat16(x[0]);
    u.h[1] = __float2bfloat16(x[1]);
    u.h[2] = __float2bfloat16(x[2]);
    u.h[3] = __float2bfloat16(x[3]);
    u.h[4] = __float2bfloat16(y[0]);
    u.h[5] = __float2bfloat16(y[1]);
    u.h[6] = __float2bfloat16(y[2]);
    u.h[7] = __float2bfloat16(y[3]);
    return u.v;
}

// ---------------------------------------------------------------------------
// Kernel 1 (fused): blocks [0,512): pack W_enc into Btt tiled:
//   short-offset = S*16384 + fr*512 + kg*128 + l15*8 holds
//   bf16 W[k = S*32+kg*8 .. +8][col = fr*16+l15]
// blocks [512,768): att2f = dec@W_dec + b_dec + b_enc.
// ---------------------------------------------------------------------------
__global__ __launch_bounds__(256) void prep_kernel(const float* __restrict__ W,
                                                   __hip_bfloat16* __restrict__ Btt,
                                                   const float* __restrict__ dec,
                                                   const float* __restrict__ W_dec,
                                                   const float* __restrict__ b_dec,
                                                   const float* __restrict__ b_enc,
                                                   float* __restrict__ att2f) {
    __shared__ float ds[DEC_DIM];
    if (blockIdx.x < 512) {
        const int gid = blockIdx.x * 256 + threadIdx.x;  // 0..131071
        const int s   = gid >> 11;        // K-step 0..63
        const int u   = gid & 2047;       // unit within step
        const int fr  = u >> 6;           // col block 0..31
        const int kg  = (u >> 4) & 3;
        const int l15 = u & 15;
        const int col = fr * 16 + l15;
        const int k0  = s * 32 + kg * 8;
        union { short8 v; __hip_bfloat16 h[8]; } x;
        #pragma unroll
        for (int i = 0; i < 8; ++i)
            x.h[i] = __float2bfloat16(W[(size_t)(k0 + i) * ATT_DIM + col]);
        *(short8*)((short*)Btt + (size_t)gid * 8) = x.v;
    } else {
        const int b = blockIdx.x - 512;
        const int t = threadIdx.x;
        ds[t]       = dec[(size_t)b * DEC_DIM + t];
        ds[t + 256] = dec[(size_t)b * DEC_DIM + t + 256];
        __syncthreads();
        #pragma unroll
        for (int j = 0; j < 2; ++j) {
            const int n = t + j * 256;
            float s = 0.f;
            #pragma unroll 8
            for (int k = 0; k < DEC_DIM; ++k)
                s += ds[k] * W_dec[(size_t)k * ATT_DIM + n];
            att2f[(size_t)b * ATT_DIM + n] = s + b_dec[n] + b_enc[n];
        }
    }
}

// ---------------------------------------------------------------------------
// Kernel 2: partial-e over a 128x256 tile.
//   e_part[nh][m] = sum_{n in half nh} relu(enc[m,:]@W_enc[:,n] + att2f[b,n]) * W_att[n]
// BM=128 x BN=256 x BK=32; 8 waves, wave tile 128x32 (acc[8][2] = 64 regs,
// 2 B-frags/wave => B-dbuf only 32 regs). B per CU halves vs BM=64 designs
// (the invariant that pinned e at ~210us). XCD-pair swizzle: the two
// N-halves of one m-tile sit 8 apart in blockIdx -> same XCD -> duplicate
// A-panel read hits XCD L2/L3, not HBM.
// A: reg-staged fp32 -> bf16 -> LDS dbuf (16 KB), depth-1 reg pipe (r13-proven).
// ---------------------------------------------------------------------------
__global__ __launch_bounds__(512, 2) void e_kernel(const float* __restrict__ enc,
                                                   const short* __restrict__ Btt,
                                                   const float* __restrict__ att2f,
                                                   const float* __restrict__ W_att,
                                                   float* __restrict__ e_part) {
    __shared__ __attribute__((aligned(16))) short As[2][4096];  // 2 x 8 KB bf16
    __shared__ float ebuf[8][128];

    const int tid  = threadIdx.x;
    const int lane = tid & 63;
    const int wv   = tid >> 6;   // 0..7 : 32-col slice within the 256-half
    const int l15  = lane & 15;
    const int kg   = lane >> 4;  // 0..3

    // XCD-pair swizzle: 784 = 49 groups x 16; r&7 -> m within group, r>>3 -> N-half.
    const int bid = blockIdx.x;
    const int g   = bid >> 4;
    const int r   = bid & 15;
    const int nh  = r >> 3;             // 0,1
    const int mt  = g * 8 + (r & 7);    // 0..391
    const int M0  = mt * BM;
    const int N0  = nh * 256;

    // A staging: thread -> (row = tid>>2, k-chunk sc = tid&3, 8 floats)
    const int srow = tid >> 2;
    const int sc   = tid & 3;
    const float* asrc = enc + (size_t)(M0 + srow) * ENC_DIM + sc * 8;
    // LDS short index: [mf=row>>4][kg=sc][l15=row&15][8]
    const int awr = (srow >> 4) * 512 + sc * 128 + (srow & 15) * 8;

    // B fragment base: frag nf of step S at short-offset
    //   S*16384 + (nh*16 + wv*2 + nf)*512 + kg*128 + l15*8
    const short* pBb = Btt + (nh * 16 + wv * 2) * 512 + kg * 128 + l15 * 8;

    f32x4 acc[8][2];
    #pragma unroll
    for (int i = 0; i < 8; ++i) {
        acc[i][0] = (f32x4){0.f, 0.f, 0.f, 0.f};
        acc[i][1] = (f32x4){0.f, 0.f, 0.f, 0.f};
    }

#define MFMA_STEP(BUF, B0, B1)                                                           \
    {                                                                                    \
        const short* Ab = &As[BUF][0];                                                   \
        _Pragma("unroll")                                                                \
        for (int mf = 0; mf < 8; ++mf) {                                                 \
            const short8 a = *(const short8*)&Ab[mf * 512 + lane * 8];                   \
            acc[mf][0] = __builtin_amdgcn_mfma_f32_16x16x32_bf16(a, B0, acc[mf][0], 0, 0, 0); \
            acc[mf][1] = __builtin_amdgcn_mfma_f32_16x16x32_bf16(a, B1, acc[mf][1], 0, 0, 0); \
        }                                                                                \
    }

    // ---- prologue: A(0)->As[0]; A(1)->avP; B(0)->c* ----
    {
        f32x4 lo = *(const f32x4*)asrc;
        f32x4 hi = *(const f32x4*)(asrc + 4);
        *(short8*)&As[0][awr] = cvt8v(lo, hi);
    }
    f32x4 avPa = *(const f32x4*)(asrc + BK);
    f32x4 avPb = *(const f32x4*)(asrc + BK + 4);
    short8 c0 = *(const short8*)(pBb);
    short8 c1 = *(const short8*)(pBb + 512);
    short8 n0, n1;
    asm volatile("s_waitcnt lgkmcnt(0)" ::: "memory");
    __builtin_amdgcn_s_barrier();

    for (int s = 0; s < NSTEP; s += 2) {
        // ==== even: read As[0], consume c*; prefetch B(s+1)->n*, A(s+2)->avN ====
        {
            const short* p1 = pBb + (size_t)(s + 1) * 16384;
            n0 = *(const short8*)(p1);
            n1 = *(const short8*)(p1 + 512);
            f32x4 avNa = *(const f32x4*)(asrc + (size_t)((s + 2) & 63) * BK);
            f32x4 avNb = *(const f32x4*)(asrc + (size_t)((s + 2) & 63) * BK + 4);
            __builtin_amdgcn_sched_barrier(0);
            __builtin_amdgcn_s_setprio(1);
            MFMA_STEP(0, c0, c1)
            __builtin_amdgcn_s_setprio(0);
            *(short8*)&As[1][awr] = cvt8v(avPa, avPb);  // A(s+1)
            avPa = avNa; avPb = avNb;
            asm volatile("s_waitcnt lgkmcnt(0)" ::: "memory");
            __builtin_amdgcn_s_barrier();
        }
        // ==== odd: read As[1], consume n*; prefetch B(s+2)->c*, A(s+3)->avN ====
        {
            const short* p2 = pBb + (size_t)((s + 2) & 63) * 16384;
            c0 = *(const short8*)(p2);
            c1 = *(const short8*)(p2 + 512);
            f32x4 avNa = *(const f32x4*)(asrc + (size_t)((s + 3) & 63) * BK);
            f32x4 avNb = *(const f32x4*)(asrc + (size_t)((s + 3) & 63) * BK + 4);
            __builtin_amdgcn_sched_barrier(0);
            __builtin_amdgcn_s_setprio(1);
            MFMA_STEP(1, n0, n1)
            __builtin_amdgcn_s_setprio(0);
            *(short8*)&As[0][awr] = cvt8v(avPa, avPb);  // A(s+2)
            avPa = avNa; avPb = avNb;
            asm volatile("s_waitcnt lgkmcnt(0)" ::: "memory");
            __builtin_amdgcn_s_barrier();
        }
    }
#undef MFMA_STEP

    // epilogue: + att2, relu, * W_att, partial reduce over this block's 256 cols
    float wat[2];
    wat[0] = W_att[N0 + wv * 32 + l15];
    wat[1] = W_att[N0 + wv * 32 + 16 + l15];

    #pragma unroll
    for (int mf = 0; mf < 8; ++mf) {
        #pragma unroll
        for (int rr = 0; rr < 4; ++rr) {
            const int ml = mf * 16 + kg * 4 + rr;   // local row 0..127
            const int bb = (M0 + ml) / NP;
            const float* arow2 = att2f + (size_t)bb * ATT_DIM + N0 + wv * 32 + l15;
            float sv = fmaxf(acc[mf][0][rr] + arow2[0], 0.f) * wat[0] +
                       fmaxf(acc[mf][1][rr] + arow2[16], 0.f) * wat[1];
            sv += __shfl_xor(sv, 1);
            sv += __shfl_xor(sv, 2);
            sv += __shfl_xor(sv, 4);
            sv += __shfl_xor(sv, 8);
            if (l15 == 0) ebuf[wv][ml] = sv;
        }
    }
    __syncthreads();
    if (tid < 128) {
        float sv = 0.f;
        #pragma unroll
        for (int w = 0; w < 8; ++w) sv += ebuf[w][tid];
        e_part[(size_t)nh * M_TOT + M0 + tid] = sv;
    }
}

// ---------------------------------------------------------------------------
// Kernel 3: per-batch softmax over 196 pixels (summing the two e-partials)
// + z[b,:] = sum_p alpha[b,p]*enc[b,p,:]. grid (256,2), float4/thread.
// ---------------------------------------------------------------------------
__global__ __launch_bounds__(256) void z_kernel(const float* __restrict__ enc,
                                                const float* __restrict__ e_part,
                                                float* __restrict__ z,
                                                float* __restrict__ alpha) {
    const int b  = blockIdx.x;
    const int cb = blockIdx.y;
    const int t  = threadIdx.x;
    __shared__ float al[NP];
    __shared__ float red[4];

    float ev = -1e30f;
    if (t < NP)
        ev = e_part[(size_t)b * NP + t] + e_part[(size_t)M_TOT + b * NP + t];
    float m = ev;
    #pragma unroll
    for (int o = 32; o > 0; o >>= 1) m = fmaxf(m, __shfl_xor(m, o));
    if ((t & 63) == 0) red[t >> 6] = m;
    __syncthreads();
    m = fmaxf(fmaxf(red[0], red[1]), fmaxf(red[2], red[3]));
    __syncthreads();
    float ex = (t < NP) ? __expf(ev - m) : 0.f;
    float s = ex;
    #pragma unroll
    for (int o = 32; o > 0; o >>= 1) s += __shfl_xor(s, o);
    if ((t & 63) == 0) red[t >> 6] = s;
    __syncthreads();
    s = red[0] + red[1] + red[2] + red[3];
    const float a = ex * (1.0f / s);
    if (t < NP) {
        al[t] = a;
        if (cb == 0) alpha[(size_t)b * NP + t] = a;
    }
    __syncthreads();

    const int c0 = cb * 1024 + t * 4;
    const float4* ep = (const float4*)(enc + (size_t)b * NP * ENC_DIM + c0);
    float4 z0 = make_float4(0.f, 0.f, 0.f, 0.f);
    float4 z1 = make_float4(0.f, 0.f, 0.f, 0.f);
    #pragma unroll 4
    for (int p = 0; p < NP; p += 2) {
        const float a0 = al[p];
        const float a1 = al[p + 1];
        const float4 v0 = ep[(size_t)p * (ENC_DIM / 4)];
        const float4 v1 = ep[(size_t)(p + 1) * (ENC_DIM / 4)];
        z0.x += a0 * v0.x; z0.y += a0 * v0.y; z0.z += a0 * v0.z; z0.w += a0 * v0.w;
        z1.x += a1 * v1.x; z1.y += a1 * v1.y; z1.z += a1 * v1.z; z1.w += a1 * v1.w;
    }
    z0.x += z1.x; z0.y += z1.y; z0.z += z1.z; z0.w += z1.w;
    *(float4*)(z + (size_t)b * ENC_DIM + c0) = z0;
}

// ---------------------------------------------------------------------------
extern "C" void kernel_launch(void* const* d_in, const int* in_sizes, int n_in,
                              void* d_out, int out_size, void* d_ws, size_t ws_size,
                              hipStream_t stream) {
    const float* enc   = (const float*)d_in[0];  // (256,196,2048)
    const float* dec   = (const float*)d_in[1];  // (256,512)
    const float* W_enc = (const float*)d_in[2];  // (2048,512)
    const float* b_enc = (const float*)d_in[3];  // (512)
    const float* W_dec = (const float*)d_in[4];  // (512,512)
    const float* b_dec = (const float*)d_in[5];  // (512)
    const float* W_att = (const float*)d_in[6];  // (512,1)
    // d_in[7] = b_att: softmax-invariant, unused.

    float* z     = (float*)d_out;                 // 256*2048
    float* alpha = z + (size_t)NB * ENC_DIM;      // 256*196

    char* ws = (char*)d_ws;
    __hip_bfloat16* Btt = (__hip_bfloat16*)ws;                        // 2 MB
    float* att2f        = (float*)(ws + 2 * 1024 * 1024);             // 512 KB
    float* e_part       = (float*)(ws + 2 * 1024 * 1024 + 512 * 1024);// 2 x 196 KB

    prep_kernel<<<768, 256, 0, stream>>>(W_enc, Btt, dec, W_dec, b_dec, b_enc, att2f);
    e_kernel<<<(M_TOT / BM) * 2, 512, 0, stream>>>(enc, (const short*)Btt, att2f, W_att, e_part);
    z_kernel<<<dim3(NB, 2), 256, 0, stream>>>(enc, e_part, z, alpha);
}

// Round 16
// 288.272 us; speedup vs baseline: 1.0375x; 1.0172x over previous
//
#include <hip/hip_runtime.h>
#include <hip/hip_bf16.h>

#define ENC_DIM 2048
#define DEC_DIM 512
#define ATT_DIM 512
#define NB 256
#define NP 196
#define BK 32
#define NSTEP (ENC_DIM / BK)  // 64

typedef __attribute__((ext_vector_type(8))) short short8;
typedef __attribute__((ext_vector_type(4))) float f32x4;

__device__ __forceinline__ short8 cvt8v(f32x4 x, f32x4 y) {
    union { short8 v; __hip_bfloat16 h[8]; } u;
    u.h[0] = __float2bfloat16(x[0]);
    u.h[1] = __float2bfloat16(x[1]);
    u.h[2] = __float2bfloat16(x[2]);
    u.h[3] = __float2bfloat16(x[3]);
    u.h[4] = __float2bfloat16(y[0]);
    u.h[5] = __float2bfloat16(y[1]);
    u.h[6] = __float2bfloat16(y[2]);
    u.h[7] = __float2bfloat16(y[3]);
    return u.v;
}

// ---------------------------------------------------------------------------
// Kernel 1 (fused prep): blocks [0,512): pack W_enc into Btt tiled:
//   short-offset = S*16384 + fr*512 + kg*128 + l15*8 holds
//   bf16 W[k = S*32+kg*8 .. +8][col = fr*16+l15]
// => B fragment fr of K-step S is one contiguous 1KB wave load from L2.
// blocks [512,768): att2f = dec@W_dec + b_dec + b_enc.
// ---------------------------------------------------------------------------
__global__ __launch_bounds__(256) void prep_kernel(const float* __restrict__ W,
                                                   __hip_bfloat16* __restrict__ Btt,
                                                   const float* __restrict__ dec,
                                                   const float* __restrict__ W_dec,
                                                   const float* __restrict__ b_dec,
                                                   const float* __restrict__ b_enc,
                                                   float* __restrict__ att2f) {
    __shared__ float ds[DEC_DIM];
    if (blockIdx.x < 512) {
        const int gid = blockIdx.x * 256 + threadIdx.x;  // 0..131071
        const int s   = gid >> 11;        // K-step 0..63
        const int u   = gid & 2047;       // unit within step
        const int fr  = u >> 6;           // col block 0..31
        const int kg  = (u >> 4) & 3;
        const int l15 = u & 15;
        const int col = fr * 16 + l15;
        const int k0  = s * 32 + kg * 8;
        union { short8 v; __hip_bfloat16 h[8]; } x;
        #pragma unroll
        for (int i = 0; i < 8; ++i)
            x.h[i] = __float2bfloat16(W[(size_t)(k0 + i) * ATT_DIM + col]);
        *(short8*)((short*)Btt + (size_t)gid * 8) = x.v;
    } else {
        const int b = blockIdx.x - 512;
        const int t = threadIdx.x;
        ds[t]       = dec[(size_t)b * DEC_DIM + t];
        ds[t + 256] = dec[(size_t)b * DEC_DIM + t + 256];
        __syncthreads();
        #pragma unroll
        for (int j = 0; j < 2; ++j) {
            const int n = t + j * 256;
            float s = 0.f;
            #pragma unroll 8
            for (int k = 0; k < DEC_DIM; ++k)
                s += ds[k] * W_dec[(size_t)k * ATT_DIM + n];
            att2f[(size_t)b * ATT_DIM + n] = s + b_dec[n] + b_enc[n];
        }
    }
}

// ---------------------------------------------------------------------------
// GEMM chunk for the fused kernel: MF m-fragments (MF*16 rows at prow0),
// full N=512 and K=2048. r13-proven loop: A reg-staged fp32->bf16->LDS dbuf,
// B single-buffered L2->regs from pre-tiled Btt, one barrier/step.
// Writes e[p] (p = prow0 + local row, p < 196) into e_lds.
// ---------------------------------------------------------------------------
template<int MF>
__device__ __forceinline__ void run_chunk(const float* __restrict__ encB,
                                          const short* __restrict__ Btt,
                                          const float* __restrict__ att2b,
                                          const float* __restrict__ W_att,
                                          short (*As)[4096],
                                          float (*ebuf)[128],
                                          float* e_lds,
                                          int prow0, int tid) {
    const int lane = tid & 63;
    const int wv   = tid >> 6;   // 0..7 : 64-col slice
    const int l15  = lane & 15;
    const int kg   = lane >> 4;  // 0..3

    // A staging: thread -> (row = tid>>2 of 128 staged rows, k-chunk = tid&3, 8 floats)
    const int srow = tid >> 2;
    const int p    = prow0 + srow;
    const int cp   = p > (NP - 1) ? (NP - 1) : p;   // clamp pad rows in-bounds
    const float* asrc = encB + (size_t)cp * ENC_DIM + (tid & 3) * 8;
    // LDS short index: [mf=srow>>4][kg=tid&3][l15=srow&15][8]
    const int awr = (srow >> 4) * 512 + (tid & 3) * 128 + (srow & 15) * 8;

    // B fragment base: frag nf of step s at short-offset s*16384 + (wv*4+nf)*512 + kg*128 + l15*8
    const short* pBb = Btt + wv * 2048 + kg * 128 + l15 * 8;

    f32x4 acc[MF][4];
    #pragma unroll
    for (int i = 0; i < MF; ++i)
        #pragma unroll
        for (int j = 0; j < 4; ++j)
            acc[i][j] = (f32x4){0.f, 0.f, 0.f, 0.f};

    // prologue: A(0) -> As[0]; A(1) -> avP
    {
        f32x4 lo = *(const f32x4*)asrc;
        f32x4 hi = *(const f32x4*)(asrc + 4);
        *(short8*)&As[0][awr] = cvt8v(lo, hi);
    }
    f32x4 avPa = *(const f32x4*)(asrc + BK);
    f32x4 avPb = *(const f32x4*)(asrc + BK + 4);
    asm volatile("s_waitcnt lgkmcnt(0)" ::: "memory");
    __builtin_amdgcn_s_barrier();

    const short* Ac = &As[0][0];
    short*       An = &As[1][0];

    for (int s = 0; s < NSTEP; ++s) {
        const short* pbs = pBb + (size_t)s * 16384;
        const short8 c0 = *(const short8*)(pbs);
        const short8 c1 = *(const short8*)(pbs + 512);
        const short8 c2 = *(const short8*)(pbs + 1024);
        const short8 c3 = *(const short8*)(pbs + 1536);
        f32x4 avNa = *(const f32x4*)(asrc + (size_t)((s + 2) & 63) * BK);
        f32x4 avNb = *(const f32x4*)(asrc + (size_t)((s + 2) & 63) * BK + 4);
        __builtin_amdgcn_sched_barrier(0);

        __builtin_amdgcn_s_setprio(1);
        #pragma unroll
        for (int mf = 0; mf < MF; ++mf) {
            const short8 a = *(const short8*)&Ac[mf * 512 + lane * 8];
            acc[mf][0] = __builtin_amdgcn_mfma_f32_16x16x32_bf16(a, c0, acc[mf][0], 0, 0, 0);
            acc[mf][1] = __builtin_amdgcn_mfma_f32_16x16x32_bf16(a, c1, acc[mf][1], 0, 0, 0);
            acc[mf][2] = __builtin_amdgcn_mfma_f32_16x16x32_bf16(a, c2, acc[mf][2], 0, 0, 0);
            acc[mf][3] = __builtin_amdgcn_mfma_f32_16x16x32_bf16(a, c3, acc[mf][3], 0, 0, 0);
        }
        __builtin_amdgcn_s_setprio(0);

        // A(s+1) into the buffer not being read this step
        *(short8*)&An[awr] = cvt8v(avPa, avPb);
        avPa = avNa; avPb = avNb;
        asm volatile("s_waitcnt lgkmcnt(0)" ::: "memory");
        __builtin_amdgcn_s_barrier();
        const short* tmp = Ac; Ac = An; An = (short*)tmp;
    }

    // epilogue: + att2, relu, * W_att, reduce over this wave's 64 cols
    float wat[4];
    #pragma unroll
    for (int nf = 0; nf < 4; ++nf) wat[nf] = W_att[wv * 64 + nf * 16 + l15];
    const float* arow2 = att2b + wv * 64 + l15;

    #pragma unroll
    for (int mf = 0; mf < MF; ++mf) {
        #pragma unroll
        for (int rr = 0; rr < 4; ++rr) {
            const int ml = mf * 16 + kg * 4 + rr;   // local row 0..MF*16-1
            float sv = 0.f;
            #pragma unroll
            for (int nf = 0; nf < 4; ++nf) {
                float v = acc[mf][nf][rr] + arow2[nf * 16];
                sv += fmaxf(v, 0.f) * wat[nf];
            }
            sv += __shfl_xor(sv, 1);
            sv += __shfl_xor(sv, 2);
            sv += __shfl_xor(sv, 4);
            sv += __shfl_xor(sv, 8);
            if (l15 == 0) ebuf[wv][ml] = sv;
        }
    }
    __syncthreads();
    if (tid < MF * 16) {
        float sv = 0.f;
        #pragma unroll
        for (int w = 0; w < 8; ++w) sv += ebuf[w][tid];
        const int pp = prow0 + tid;
        if (pp < NP) e_lds[pp] = sv;
    }
    __syncthreads();
}

// ---------------------------------------------------------------------------
// Kernel 2 (FUSED e + softmax + z): one block per batch (grid=256=1/CU).
// GEMM chunks {112, 96} rows -> e in LDS -> in-block softmax -> z-phase
// re-reads enc[b] (1.6 MB, L2/L3-hot from the GEMM pass: chip-wide chunk
// working set ~115-230 MB <= 256 MB L3). enc touches HBM once, not twice.
// ---------------------------------------------------------------------------
__global__ __launch_bounds__(512, 2) void fused_kernel(const float* __restrict__ enc,
                                                       const short* __restrict__ Btt,
                                                       const float* __restrict__ att2f,
                                                       const float* __restrict__ W_att,
                                                       float* __restrict__ z,
                                                       float* __restrict__ alpha) {
    __shared__ __attribute__((aligned(16))) short As[2][4096];  // 16 KB
    __shared__ float ebuf[8][128];                              // 4 KB
    __shared__ float e_lds[NP];
    __shared__ float al[NP];
    __shared__ float red[8];

    const int tid = threadIdx.x;
    const int b   = blockIdx.x;
    const float* encB  = enc + (size_t)b * NP * ENC_DIM;
    const float* att2b = att2f + (size_t)b * ATT_DIM;

    // ---- phase 1: e-GEMM in two chunks (112 + 96 rows, 196 valid) ----
    run_chunk<7>(encB, Btt, att2b, W_att, As, ebuf, e_lds, 0,   tid);
    run_chunk<6>(encB, Btt, att2b, W_att, As, ebuf, e_lds, 112, tid);

    // ---- phase 2: softmax over 196 pixels (8-wave block reduction) ----
    const int lane = tid & 63;
    const int wv   = tid >> 6;
    float ev = (tid < NP) ? e_lds[tid] : -1e30f;
    float m = ev;
    #pragma unroll
    for (int o = 32; o > 0; o >>= 1) m = fmaxf(m, __shfl_xor(m, o));
    if (lane == 0) red[wv] = m;
    __syncthreads();
    m = red[0];
    #pragma unroll
    for (int w = 1; w < 8; ++w) m = fmaxf(m, red[w]);
    __syncthreads();
    float ex = (tid < NP) ? __expf(ev - m) : 0.f;
    float sum = ex;
    #pragma unroll
    for (int o = 32; o > 0; o >>= 1) sum += __shfl_xor(sum, o);
    if (lane == 0) red[wv] = sum;
    __syncthreads();
    sum = red[0] + red[1] + red[2] + red[3] + red[4] + red[5] + red[6] + red[7];
    const float a = ex * (1.0f / sum);
    if (tid < NP) {
        al[tid] = a;
        alpha[(size_t)b * NP + tid] = a;
    }
    __syncthreads();

    // ---- phase 3: z[b,c] = sum_p al[p] * enc[b,p,c]; enc[b] is L2/L3-hot ----
    const int c0 = tid * 4;   // 512 threads x 4 cols = 2048
    const float4* ep = (const float4*)(encB + c0);
    float4 z0 = make_float4(0.f, 0.f, 0.f, 0.f);
    float4 z1 = make_float4(0.f, 0.f, 0.f, 0.f);
    #pragma unroll 2
    for (int p = 0; p < NP; p += 2) {
        const float a0 = al[p];
        const float a1 = al[p + 1];
        const float4 v0 = ep[(size_t)p * (ENC_DIM / 4)];
        const float4 v1 = ep[(size_t)(p + 1) * (ENC_DIM / 4)];
        z0.x += a0 * v0.x; z0.y += a0 * v0.y; z0.z += a0 * v0.z; z0.w += a0 * v0.w;
        z1.x += a1 * v1.x; z1.y += a1 * v1.y; z1.z += a1 * v1.z; z1.w += a1 * v1.w;
    }
    z0.x += z1.x; z0.y += z1.y; z0.z += z1.z; z0.w += z1.w;
    *(float4*)(z + (size_t)b * ENC_DIM + c0) = z0;
}

// ---------------------------------------------------------------------------
extern "C" void kernel_launch(void* const* d_in, const int* in_sizes, int n_in,
                              void* d_out, int out_size, void* d_ws, size_t ws_size,
                              hipStream_t stream) {
    const float* enc   = (const float*)d_in[0];  // (256,196,2048)
    const float* dec   = (const float*)d_in[1];  // (256,512)
    const float* W_enc = (const float*)d_in[2];  // (2048,512)
    const float* b_enc = (const float*)d_in[3];  // (512)
    const float* W_dec = (const float*)d_in[4];  // (512,512)
    const float* b_dec = (const float*)d_in[5];  // (512)
    const float* W_att = (const float*)d_in[6];  // (512,1)
    // d_in[7] = b_att: softmax-invariant, unused.

    float* z     = (float*)d_out;                 // 256*2048
    float* alpha = z + (size_t)NB * ENC_DIM;      // 256*196

    char* ws = (char*)d_ws;
    __hip_bfloat16* Btt = (__hip_bfloat16*)ws;                // 2 MB
    float* att2f        = (float*)(ws + 2 * 1024 * 1024);     // 512 KB

    prep_kernel<<<768, 256, 0, stream>>>(W_enc, Btt, dec, W_dec, b_dec, b_enc, att2f);
    fused_kernel<<<NB, 512, 0, stream>>>(enc, (const short*)Btt, att2f, W_att, z, alpha);
}